// Round 7
// baseline (113.071 us; speedup 1.0000x reference)
//
#include <hip/hip_runtime.h>
#include <hip/hip_bf16.h>

#define NB 8
#define NS 4096
#define ND 1280
#define NR 64
#define EW 6656   // D + R*R + D

typedef __attribute__((ext_vector_type(4))) float f4;
typedef __attribute__((ext_vector_type(8))) short bf8;

union BF8U { bf8 v; unsigned u[4]; };

__device__ __forceinline__ unsigned short f2bf(float f) {
  union { float f; unsigned u; } v; v.f = f;
  unsigned u = v.u + 0x7FFFu + ((v.u >> 16) & 1u);  // RNE
  return (unsigned short)(u >> 16);
}

__device__ __forceinline__ unsigned pk2(float a, float b) {
  __hip_bfloat162 t = __float22bfloat162_rn(float2{a, b});   // v_cvt_pk_bf16_f32
  return *reinterpret_cast<unsigned*>(&t);
}

// ---------------- prep: W2F, W3FB (per-batch, up_w folded), h2bias ----------------
// (unchanged from R6 — passed)
__global__ __launch_bounds__(256) void prep_all(const float* __restrict__ embed,
                                                const float* __restrict__ w_down,
                                                const float* __restrict__ w_up,
                                                const float* __restrict__ b_down,
                                                unsigned short* __restrict__ W2F,
                                                unsigned short* __restrict__ W3FB,
                                                float* __restrict__ h2bias) {
  const int blk = blockIdx.x;
  const int t   = threadIdx.x;
  if (blk < 160) {
    const int b  = blk / 20;
    const int qg = (blk % 20) / 5;
    const int dg = blk % 5;
    __shared__ float mids[16][64];
    #pragma unroll
    for (int i = 0; i < 4; ++i) {
      int idx = t + i * 256;
      mids[idx >> 6][idx & 63] = embed[b * EW + ND + qg * 1024 + idx];
    }
    __syncthreads();
    const int d = dg * 256 + t;
    float acc[16];
    #pragma unroll
    for (int q = 0; q < 16; ++q) acc[q] = 0.f;
    for (int r = 0; r < 64; r += 8) {
      float wd[8];
      #pragma unroll
      for (int u = 0; u < 8; ++u) wd[u] = w_down[(r + u) * ND + d];
      #pragma unroll
      for (int u = 0; u < 8; ++u)
        #pragma unroll
        for (int q = 0; q < 16; ++q) acc[q] += mids[q][r + u] * wd[u];
    }
    const float dwn = embed[b * EW + d];
    const int kt = d >> 5, lanehi = (d & 31) >> 3, jj = d & 7;
    #pragma unroll
    for (int q = 0; q < 16; ++q)
      W2F[(((b * 40 + kt) * 4 + qg) << 9) + (lanehi * 16 + q) * 8 + jj] = f2bf(acc[q] * dwn);
  } else if (blk < 2720) {
    const int local = blk - 160;
    const int b  = local / 320;
    const int g  = (local % 320) * 256 + t;   // g = d*64 + q
    const int d  = g >> 6, q = g & 63;
    const int kt = q >> 5, nt = d >> 4;
    const int lanei = ((q & 31) >> 3) * 16 + (d & 15), jj = q & 7;
    const float upw = embed[b * EW + 5376 + d];
    W3FB[(size_t)b * 81920 + ((kt * 80 + nt) * 64 + lanei) * 8 + jj] = f2bf(w_up[g] * upw);
  } else {
    #pragma unroll
    for (int ii = 0; ii < 2; ++ii) {
      int id = ii * 256 + t;                  // id = b*64 + q
      int bb = id >> 6, q = id & 63;
      float s = 0.f;
      for (int r = 0; r < 64; ++r) s += b_down[r] * embed[bb * EW + ND + q * 64 + r];
      h2bias[id] = s;
    }
  }
}

// ---------------- mega: block-local fusion of k1 + k2 ----------------
// Block = 32 rows of one batch. P1 (R6 k1 body) -> h2 frags exchanged via
// 4KB LDS (pkx) -> P2 (R6 k2 body). No h2F HBM round trip, no kernel gap,
// no global drain between phases. Internals of both phases unchanged.
__global__ __launch_bounds__(256, 4) void mega(const float* __restrict__ x,
                                               const float* __restrict__ embed,
                                               const float* __restrict__ b_up,
                                               const unsigned short* __restrict__ W2F,
                                               const unsigned short* __restrict__ W3FB,
                                               const float* __restrict__ h2bias,
                                               float* __restrict__ out) {
  const int tid  = threadIdx.x;
  const int lane = tid & 63;
  const int w    = tid >> 6;
  const int kh   = w >> 1;                // P1: K-half. P2: d-half.
  const int rt   = w & 1;                 // row-tile 0/1
  const int b    = blockIdx.x & 7;        // batch -> XCD round-robin
  const int tile = blockIdx.x >> 3;       // 0..127
  const int lo16 = lane & 15;
  const int hi4  = lane >> 4;
  const int wrow = tile * 32 + rt * 16;

  // LDS plan:
  //  pool[0,32768): P1 xs (wave-private dbuf) -> h2p [0,17408) -> P2 ldsT [0,9216)
  //  pool[28672,32768): pkx (written only after both post-P1 barriers)
  //  pbs, hb: separate (staged during P1's DMA shadow)
  __shared__ __align__(16) char pool[32768];
  __shared__ __align__(16) float pbs[1280];
  __shared__ float hb[64];
  float (*xs)[2][1024]    = (float (*)[2][1024])pool;
  float (*h2p)[2][16][68] = (float (*)[2][16][68])pool;
  float (*ldsT)[16][36]   = (float (*)[16][36])pool;
  uint4* pkx              = (uint4*)(pool + 28672);

  // early staging (vmem ops here are OLDER than the P1 pipeline's -> vmcnt(12) unaffected)
  if (tid < 64) hb[tid] = h2bias[b * 64 + tid];
  {
    const float* upw = embed + b * EW + 5376;
    #pragma unroll
    for (int i = 0; i < 5; ++i) {
      const int idx = i * 256 + tid;
      pbs[idx] = b_up[idx] * upw[idx];
    }
  }

  // ================= P1: h2 partials (identical to R6 k1) =================
  const float* xbase = x + ((size_t)b * NS + wrow) * ND + kh * 640;
  const unsigned short* w2b = W2F + (size_t)b * 81920;

  #define ISSUE_DMA(ck, buf)                                                         \
    _Pragma("unroll")                                                                \
    for (int it = 0; it < 4; ++it) {                                                 \
      const int rloc = it * 4 + hi4;                                                 \
      const int cf   = lo16 ^ rloc;                                                  \
      const float* src = xbase + (size_t)rloc * ND + (ck) * 64 + cf * 4;             \
      __builtin_amdgcn_global_load_lds((__attribute__((address_space(1))) void*)src, \
          (__attribute__((address_space(3))) void*)&xs[w][buf][it * 256], 16, 0, 0); \
    }

  f4 acc[4] = {};
  bf8 bw[8];

  ISSUE_DMA(0, 0)
  {
    const unsigned short* wp = w2b + (((kh * 10) * 8) << 9) + lane * 8;
    #pragma unroll
    for (int i = 0; i < 8; ++i) bw[i] = *(const bf8*)(wp + (i << 9));
  }

  for (int ck = 0; ck < 10; ++ck) {
    const int buf = ck & 1;
    bf8 bn[8];
    if (ck < 9) {
      ISSUE_DMA(ck + 1, buf ^ 1)
      const unsigned short* wp = w2b + (size_t)(((kh * 10 + ck + 1) * 8) << 9) + lane * 8;
      #pragma unroll
      for (int i = 0; i < 8; ++i) bn[i] = *(const bf8*)(wp + (i << 9));
      asm volatile("s_waitcnt vmcnt(12)" ::: "memory");
    } else {
      asm volatile("s_waitcnt vmcnt(0)" ::: "memory");
    }
    const f4* xp = (const f4*)&xs[w][buf][0];
    f4 a0 = xp[lo16 * 16 + ((hi4 * 2)     ^ lo16)];
    f4 a1 = xp[lo16 * 16 + ((hi4 * 2 + 1) ^ lo16)];
    f4 a2 = xp[lo16 * 16 + ((hi4 * 2 + 8) ^ lo16)];
    f4 a3 = xp[lo16 * 16 + ((hi4 * 2 + 9) ^ lo16)];
    BF8U af0, af1;
    af0.u[0] = pk2(a0[0], a0[1]); af0.u[1] = pk2(a0[2], a0[3]);
    af0.u[2] = pk2(a1[0], a1[1]); af0.u[3] = pk2(a1[2], a1[3]);
    af1.u[0] = pk2(a2[0], a2[1]); af1.u[1] = pk2(a2[2], a2[3]);
    af1.u[2] = pk2(a3[0], a3[1]); af1.u[3] = pk2(a3[2], a3[3]);
    #pragma unroll
    for (int nt = 0; nt < 4; ++nt)
      acc[nt] = __builtin_amdgcn_mfma_f32_16x16x32_bf16(af0.v, bw[nt], acc[nt], 0, 0, 0);
    #pragma unroll
    for (int nt = 0; nt < 4; ++nt)
      acc[nt] = __builtin_amdgcn_mfma_f32_16x16x32_bf16(af1.v, bw[4 + nt], acc[nt], 0, 0, 0);
    if (ck < 9) {
      #pragma unroll
      for (int i = 0; i < 8; ++i) bw[i] = bn[i];
    }
  }

  __syncthreads();   // all waves done with xs; pool becomes h2p

  #pragma unroll
  for (int nt = 0; nt < 4; ++nt)
    #pragma unroll
    for (int j = 0; j < 4; ++j)
      h2p[kh][rt][hi4 * 4 + j][nt * 16 + lo16] = acc[nt][j];
  __syncthreads();

  // combine K-halves + bias -> bf16 frag; exchange via pkx (replaces h2F)
  {
    const int q0 = kh * 32 + hi4 * 8;
    f4 u0 = *(const f4*)&h2p[0][rt][lo16][q0];
    f4 u1 = *(const f4*)&h2p[0][rt][lo16][q0 + 4];
    f4 v0 = *(const f4*)&h2p[1][rt][lo16][q0];
    f4 v1 = *(const f4*)&h2p[1][rt][lo16][q0 + 4];
    float s[8];
    #pragma unroll
    for (int j = 0; j < 4; ++j) {
      s[j]     = u0[j] + v0[j] + hb[q0 + j];
      s[4 + j] = u1[j] + v1[j] + hb[q0 + 4 + j];
    }
    uint4 pk;
    pk.x = pk2(s[0], s[1]); pk.y = pk2(s[2], s[3]);
    pk.z = pk2(s[4], s[5]); pk.w = pk2(s[6], s[7]);
    pkx[(rt * 2 + kh) * 64 + lane] = pk;
  }
  __syncthreads();

  // ================= P2: output streamer (identical to R6 k2) =================
  BF8U ha0, ha1;
  {
    uint4 hv0 = pkx[(rt * 2 + 0) * 64 + lane];
    uint4 hv1 = pkx[(rt * 2 + 1) * 64 + lane];
    ha0.u[0] = hv0.x; ha0.u[1] = hv0.y; ha0.u[2] = hv0.z; ha0.u[3] = hv0.w;
    ha1.u[0] = hv1.x; ha1.u[1] = hv1.y; ha1.u[2] = hv1.z; ha1.u[3] = hv1.w;
  }

  const unsigned short* w3b = W3FB + (size_t)b * 81920;
  float* outp = out + ((size_t)b * NS + tile * 32 + rt * 16) * ND + kh * 640;
  const int dtbase = kh * 40;

  bf8 wb00 = *(const bf8*)(w3b + (size_t)((dtbase)          * 64 + lane) * 8);
  bf8 wb01 = *(const bf8*)(w3b + (size_t)((80 + dtbase)     * 64 + lane) * 8);
  bf8 wb10 = *(const bf8*)(w3b + (size_t)((dtbase + 1)      * 64 + lane) * 8);
  bf8 wb11 = *(const bf8*)(w3b + (size_t)((80 + dtbase + 1) * 64 + lane) * 8);

  for (int c = 0; c < 20; ++c) {
    // prefetch next step FIRST (max latency cover; waits later are vmcnt(2), no store-wait)
    bf8 wn00, wn01, wn10, wn11;
    if (c < 19) {
      const int dt = dtbase + (c + 1) * 2;
      wn00 = *(const bf8*)(w3b + (size_t)(dt * 64 + lane) * 8);
      wn01 = *(const bf8*)(w3b + (size_t)((80 + dt) * 64 + lane) * 8);
      wn10 = *(const bf8*)(w3b + (size_t)((dt + 1) * 64 + lane) * 8);
      wn11 = *(const bf8*)(w3b + (size_t)((80 + dt + 1) * 64 + lane) * 8);
    }
    f4 o0 = {}, o1 = {};
    o0 = __builtin_amdgcn_mfma_f32_16x16x32_bf16(wb00, ha0.v, o0, 0, 0, 0);
    o0 = __builtin_amdgcn_mfma_f32_16x16x32_bf16(wb01, ha1.v, o0, 0, 0, 0);
    o1 = __builtin_amdgcn_mfma_f32_16x16x32_bf16(wb10, ha0.v, o1, 0, 0, 0);
    o1 = __builtin_amdgcn_mfma_f32_16x16x32_bf16(wb11, ha1.v, o1, 0, 0, 0);
    // epilogue: + (b_up*up_w) -> per-wave LDS transpose
    #pragma unroll
    for (int i = 0; i < 2; ++i) {
      const f4 oi = i ? o1 : o0;
      const int dl = kh * 640 + c * 32 + i * 16 + hi4 * 4;
      f4 pbv = *(const f4*)&pbs[dl];
      f4 r;
      #pragma unroll
      for (int j = 0; j < 4; ++j) r[j] = oi[j] + pbv[j];
      *(f4*)&ldsT[w][lo16][i * 16 + hi4 * 4] = r;
    }
    // 2 stores/iter: 8 rows x 128B contiguous segments each
    #pragma unroll
    for (int k = 0; k < 2; ++k) {
      const int rr = k * 8 + (lane >> 3);
      f4 v = *(const f4*)&ldsT[w][rr][(lane & 7) * 4];
      *(f4*)(outp + (size_t)rr * ND + c * 32 + (lane & 7) * 4) = v;
    }
    wb00 = wn00; wb01 = wn01; wb10 = wn10; wb11 = wn11;
  }
}

extern "C" void kernel_launch(void* const* d_in, const int* in_sizes, int n_in,
                              void* d_out, int out_size, void* d_ws, size_t ws_size,
                              hipStream_t stream) {
  const float* x      = (const float*)d_in[0];
  const float* embed  = (const float*)d_in[1];
  const float* w_down = (const float*)d_in[2];
  const float* b_down = (const float*)d_in[3];
  const float* w_up   = (const float*)d_in[4];
  const float* b_up   = (const float*)d_in[5];
  float* out = (float*)d_out;

  char* ws = (char*)d_ws;
  unsigned short* W2F  = (unsigned short*)ws;                // 1,310,720 B
  unsigned short* W3FB = (unsigned short*)(ws + 1310720);    // 1,310,720 B
  float* h2bias        = (float*)(ws + 2621440);             //     2,048 B

  prep_all<<<2721, 256, 0, stream>>>(embed, w_down, w_up, b_down, W2F, W3FB, h2bias);
  mega    <<<1024, 256, 0, stream>>>(x, embed, b_up, W2F, W3FB, h2bias, out);
}

// Round 8
// 110.396 us; speedup vs baseline: 1.0242x; 1.0242x over previous
//
#include <hip/hip_runtime.h>
#include <hip/hip_bf16.h>

#define NB 8
#define NS 4096
#define ND 1280
#define NR 64
#define EW 6656   // D + R*R + D

typedef __attribute__((ext_vector_type(4))) float f4;
typedef __attribute__((ext_vector_type(8))) short bf8;

union BF8U { bf8 v; unsigned u[4]; };

__device__ __forceinline__ unsigned short f2bf(float f) {
  union { float f; unsigned u; } v; v.f = f;
  unsigned u = v.u + 0x7FFFu + ((v.u >> 16) & 1u);  // RNE
  return (unsigned short)(u >> 16);
}

__device__ __forceinline__ unsigned pk2(float a, float b) {
  __hip_bfloat162 t = __float22bfloat162_rn(float2{a, b});   // v_cvt_pk_bf16_f32
  return *reinterpret_cast<unsigned*>(&t);
}

// ---------------- prep: W2F, W3FB (per-batch, up_w folded), h2bias ----------------
// (unchanged from R6/R7 — passed)
__global__ __launch_bounds__(256) void prep_all(const float* __restrict__ embed,
                                                const float* __restrict__ w_down,
                                                const float* __restrict__ w_up,
                                                const float* __restrict__ b_down,
                                                unsigned short* __restrict__ W2F,
                                                unsigned short* __restrict__ W3FB,
                                                float* __restrict__ h2bias) {
  const int blk = blockIdx.x;
  const int t   = threadIdx.x;
  if (blk < 160) {
    const int b  = blk / 20;
    const int qg = (blk % 20) / 5;
    const int dg = blk % 5;
    __shared__ float mids[16][64];
    #pragma unroll
    for (int i = 0; i < 4; ++i) {
      int idx = t + i * 256;
      mids[idx >> 6][idx & 63] = embed[b * EW + ND + qg * 1024 + idx];
    }
    __syncthreads();
    const int d = dg * 256 + t;
    float acc[16];
    #pragma unroll
    for (int q = 0; q < 16; ++q) acc[q] = 0.f;
    for (int r = 0; r < 64; r += 8) {
      float wd[8];
      #pragma unroll
      for (int u = 0; u < 8; ++u) wd[u] = w_down[(r + u) * ND + d];
      #pragma unroll
      for (int u = 0; u < 8; ++u)
        #pragma unroll
        for (int q = 0; q < 16; ++q) acc[q] += mids[q][r + u] * wd[u];
    }
    const float dwn = embed[b * EW + d];
    const int kt = d >> 5, lanehi = (d & 31) >> 3, jj = d & 7;
    #pragma unroll
    for (int q = 0; q < 16; ++q)
      W2F[(((b * 40 + kt) * 4 + qg) << 9) + (lanehi * 16 + q) * 8 + jj] = f2bf(acc[q] * dwn);
  } else if (blk < 2720) {
    const int local = blk - 160;
    const int b  = local / 320;
    const int g  = (local % 320) * 256 + t;   // g = d*64 + q
    const int d  = g >> 6, q = g & 63;
    const int kt = q >> 5, nt = d >> 4;
    const int lanei = ((q & 31) >> 3) * 16 + (d & 15), jj = q & 7;
    const float upw = embed[b * EW + 5376 + d];
    W3FB[(size_t)b * 81920 + ((kt * 80 + nt) * 64 + lanei) * 8 + jj] = f2bf(w_up[g] * upw);
  } else {
    #pragma unroll
    for (int ii = 0; ii < 2; ++ii) {
      int id = ii * 256 + t;                  // id = b*64 + q
      int bb = id >> 6, q = id & 63;
      float s = 0.f;
      for (int r = 0; r < 64; ++r) s += b_down[r] * embed[bb * EW + ND + q * 64 + r];
      h2bias[id] = s;
    }
  }
}

// ---------------- mega: block-local fusion of k1 + k2 ----------------
// R8 change (ONLY change vs R7): batch/tile mapping swapped so batches are
// SPREAD across XCDs instead of pinned one-batch-per-XCD. blockIdx%8 = XCD;
// old mapping (b = blockIdx&7) forced all of batch b's x/out stream through
// one XCD's L2/fabric port (~1/8 of chip BW). New: b = blockIdx>>7.
__global__ __launch_bounds__(256, 4) void mega(const float* __restrict__ x,
                                               const float* __restrict__ embed,
                                               const float* __restrict__ b_up,
                                               const unsigned short* __restrict__ W2F,
                                               const unsigned short* __restrict__ W3FB,
                                               const float* __restrict__ h2bias,
                                               float* __restrict__ out) {
  const int tid  = threadIdx.x;
  const int lane = tid & 63;
  const int w    = tid >> 6;
  const int kh   = w >> 1;                // P1: K-half. P2: d-half.
  const int rt   = w & 1;                 // row-tile 0/1
  const int b    = blockIdx.x >> 7;       // batch (spread over XCDs)
  const int tile = blockIdx.x & 127;      // tile within batch
  const int lo16 = lane & 15;
  const int hi4  = lane >> 4;
  const int wrow = tile * 32 + rt * 16;

  // LDS plan:
  //  pool[0,32768): P1 xs (wave-private dbuf) -> h2p [0,17408) -> P2 ldsT [0,9216)
  //  pool[28672,32768): pkx (written only after both post-P1 barriers)
  //  pbs, hb: separate (staged during P1's DMA shadow)
  __shared__ __align__(16) char pool[32768];
  __shared__ __align__(16) float pbs[1280];
  __shared__ float hb[64];
  float (*xs)[2][1024]    = (float (*)[2][1024])pool;
  float (*h2p)[2][16][68] = (float (*)[2][16][68])pool;
  float (*ldsT)[16][36]   = (float (*)[16][36])pool;
  uint4* pkx              = (uint4*)(pool + 28672);

  // early staging (vmem ops here are OLDER than the P1 pipeline's -> vmcnt(12) unaffected)
  if (tid < 64) hb[tid] = h2bias[b * 64 + tid];
  {
    const float* upw = embed + b * EW + 5376;
    #pragma unroll
    for (int i = 0; i < 5; ++i) {
      const int idx = i * 256 + tid;
      pbs[idx] = b_up[idx] * upw[idx];
    }
  }

  // ================= P1: h2 partials (identical to R7) =================
  const float* xbase = x + ((size_t)b * NS + wrow) * ND + kh * 640;
  const unsigned short* w2b = W2F + (size_t)b * 81920;

  #define ISSUE_DMA(ck, buf)                                                         \
    _Pragma("unroll")                                                                \
    for (int it = 0; it < 4; ++it) {                                                 \
      const int rloc = it * 4 + hi4;                                                 \
      const int cf   = lo16 ^ rloc;                                                  \
      const float* src = xbase + (size_t)rloc * ND + (ck) * 64 + cf * 4;             \
      __builtin_amdgcn_global_load_lds((__attribute__((address_space(1))) void*)src, \
          (__attribute__((address_space(3))) void*)&xs[w][buf][it * 256], 16, 0, 0); \
    }

  f4 acc[4] = {};
  bf8 bw[8];

  ISSUE_DMA(0, 0)
  {
    const unsigned short* wp = w2b + (((kh * 10) * 8) << 9) + lane * 8;
    #pragma unroll
    for (int i = 0; i < 8; ++i) bw[i] = *(const bf8*)(wp + (i << 9));
  }

  for (int ck = 0; ck < 10; ++ck) {
    const int buf = ck & 1;
    bf8 bn[8];
    if (ck < 9) {
      ISSUE_DMA(ck + 1, buf ^ 1)
      const unsigned short* wp = w2b + (size_t)(((kh * 10 + ck + 1) * 8) << 9) + lane * 8;
      #pragma unroll
      for (int i = 0; i < 8; ++i) bn[i] = *(const bf8*)(wp + (i << 9));
      asm volatile("s_waitcnt vmcnt(12)" ::: "memory");
    } else {
      asm volatile("s_waitcnt vmcnt(0)" ::: "memory");
    }
    const f4* xp = (const f4*)&xs[w][buf][0];
    f4 a0 = xp[lo16 * 16 + ((hi4 * 2)     ^ lo16)];
    f4 a1 = xp[lo16 * 16 + ((hi4 * 2 + 1) ^ lo16)];
    f4 a2 = xp[lo16 * 16 + ((hi4 * 2 + 8) ^ lo16)];
    f4 a3 = xp[lo16 * 16 + ((hi4 * 2 + 9) ^ lo16)];
    BF8U af0, af1;
    af0.u[0] = pk2(a0[0], a0[1]); af0.u[1] = pk2(a0[2], a0[3]);
    af0.u[2] = pk2(a1[0], a1[1]); af0.u[3] = pk2(a1[2], a1[3]);
    af1.u[0] = pk2(a2[0], a2[1]); af1.u[1] = pk2(a2[2], a2[3]);
    af1.u[2] = pk2(a3[0], a3[1]); af1.u[3] = pk2(a3[2], a3[3]);
    #pragma unroll
    for (int nt = 0; nt < 4; ++nt)
      acc[nt] = __builtin_amdgcn_mfma_f32_16x16x32_bf16(af0.v, bw[nt], acc[nt], 0, 0, 0);
    #pragma unroll
    for (int nt = 0; nt < 4; ++nt)
      acc[nt] = __builtin_amdgcn_mfma_f32_16x16x32_bf16(af1.v, bw[4 + nt], acc[nt], 0, 0, 0);
    if (ck < 9) {
      #pragma unroll
      for (int i = 0; i < 8; ++i) bw[i] = bn[i];
    }
  }

  __syncthreads();   // all waves done with xs; pool becomes h2p

  #pragma unroll
  for (int nt = 0; nt < 4; ++nt)
    #pragma unroll
    for (int j = 0; j < 4; ++j)
      h2p[kh][rt][hi4 * 4 + j][nt * 16 + lo16] = acc[nt][j];
  __syncthreads();

  // combine K-halves + bias -> bf16 frag; exchange via pkx
  {
    const int q0 = kh * 32 + hi4 * 8;
    f4 u0 = *(const f4*)&h2p[0][rt][lo16][q0];
    f4 u1 = *(const f4*)&h2p[0][rt][lo16][q0 + 4];
    f4 v0 = *(const f4*)&h2p[1][rt][lo16][q0];
    f4 v1 = *(const f4*)&h2p[1][rt][lo16][q0 + 4];
    float s[8];
    #pragma unroll
    for (int j = 0; j < 4; ++j) {
      s[j]     = u0[j] + v0[j] + hb[q0 + j];
      s[4 + j] = u1[j] + v1[j] + hb[q0 + 4 + j];
    }
    uint4 pk;
    pk.x = pk2(s[0], s[1]); pk.y = pk2(s[2], s[3]);
    pk.z = pk2(s[4], s[5]); pk.w = pk2(s[6], s[7]);
    pkx[(rt * 2 + kh) * 64 + lane] = pk;
  }
  __syncthreads();

  // ================= P2: output streamer (identical to R7) =================
  BF8U ha0, ha1;
  {
    uint4 hv0 = pkx[(rt * 2 + 0) * 64 + lane];
    uint4 hv1 = pkx[(rt * 2 + 1) * 64 + lane];
    ha0.u[0] = hv0.x; ha0.u[1] = hv0.y; ha0.u[2] = hv0.z; ha0.u[3] = hv0.w;
    ha1.u[0] = hv1.x; ha1.u[1] = hv1.y; ha1.u[2] = hv1.z; ha1.u[3] = hv1.w;
  }

  const unsigned short* w3b = W3FB + (size_t)b * 81920;
  float* outp = out + ((size_t)b * NS + tile * 32 + rt * 16) * ND + kh * 640;
  const int dtbase = kh * 40;

  bf8 wb00 = *(const bf8*)(w3b + (size_t)((dtbase)          * 64 + lane) * 8);
  bf8 wb01 = *(const bf8*)(w3b + (size_t)((80 + dtbase)     * 64 + lane) * 8);
  bf8 wb10 = *(const bf8*)(w3b + (size_t)((dtbase + 1)      * 64 + lane) * 8);
  bf8 wb11 = *(const bf8*)(w3b + (size_t)((80 + dtbase + 1) * 64 + lane) * 8);

  for (int c = 0; c < 20; ++c) {
    bf8 wn00, wn01, wn10, wn11;
    if (c < 19) {
      const int dt = dtbase + (c + 1) * 2;
      wn00 = *(const bf8*)(w3b + (size_t)(dt * 64 + lane) * 8);
      wn01 = *(const bf8*)(w3b + (size_t)((80 + dt) * 64 + lane) * 8);
      wn10 = *(const bf8*)(w3b + (size_t)((dt + 1) * 64 + lane) * 8);
      wn11 = *(const bf8*)(w3b + (size_t)((80 + dt + 1) * 64 + lane) * 8);
    }
    f4 o0 = {}, o1 = {};
    o0 = __builtin_amdgcn_mfma_f32_16x16x32_bf16(wb00, ha0.v, o0, 0, 0, 0);
    o0 = __builtin_amdgcn_mfma_f32_16x16x32_bf16(wb01, ha1.v, o0, 0, 0, 0);
    o1 = __builtin_amdgcn_mfma_f32_16x16x32_bf16(wb10, ha0.v, o1, 0, 0, 0);
    o1 = __builtin_amdgcn_mfma_f32_16x16x32_bf16(wb11, ha1.v, o1, 0, 0, 0);
    #pragma unroll
    for (int i = 0; i < 2; ++i) {
      const f4 oi = i ? o1 : o0;
      const int dl = kh * 640 + c * 32 + i * 16 + hi4 * 4;
      f4 pbv = *(const f4*)&pbs[dl];
      f4 r;
      #pragma unroll
      for (int j = 0; j < 4; ++j) r[j] = oi[j] + pbv[j];
      *(f4*)&ldsT[w][lo16][i * 16 + hi4 * 4] = r;
    }
    #pragma unroll
    for (int k = 0; k < 2; ++k) {
      const int rr = k * 8 + (lane >> 3);
      f4 v = *(const f4*)&ldsT[w][rr][(lane & 7) * 4];
      *(f4*)(outp + (size_t)rr * ND + c * 32 + (lane & 7) * 4) = v;
    }
    wb00 = wn00; wb01 = wn01; wb10 = wn10; wb11 = wn11;
  }
}

extern "C" void kernel_launch(void* const* d_in, const int* in_sizes, int n_in,
                              void* d_out, int out_size, void* d_ws, size_t ws_size,
                              hipStream_t stream) {
  const float* x      = (const float*)d_in[0];
  const float* embed  = (const float*)d_in[1];
  const float* w_down = (const float*)d_in[2];
  const float* b_down = (const float*)d_in[3];
  const float* w_up   = (const float*)d_in[4];
  const float* b_up   = (const float*)d_in[5];
  float* out = (float*)d_out;

  char* ws = (char*)d_ws;
  unsigned short* W2F  = (unsigned short*)ws;                // 1,310,720 B
  unsigned short* W3FB = (unsigned short*)(ws + 1310720);    // 1,310,720 B
  float* h2bias        = (float*)(ws + 2621440);             //     2,048 B

  prep_all<<<2721, 256, 0, stream>>>(embed, w_down, w_up, b_down, W2F, W3FB, h2bias);
  mega    <<<1024, 256, 0, stream>>>(x, embed, b_up, W2F, W3FB, h2bias, out);
}